// Round 8
// baseline (192.243 us; speedup 1.0000x reference)
//
#include <hip/hip_runtime.h>

static constexpr int KM1     = 1048575;        // sampled elems kk in [0, KM1-1]
static constexpr int M_S     = 32;
static constexpr int J_IT    = 16;             // iters/wave, 128 elems each
static constexpr int SPANE   = 128 * J_IT;     // 2048 elems per chunk
static constexpr int NCHUNK  = 512;
static constexpr int OFF_MAX = 2 * (KM1 - 2);  // last safe float offset of a pair load
static constexpr int NSLOT   = 64;

typedef float f32x2 __attribute__((ext_vector_type(2)));
typedef float f32x4 __attribute__((ext_vector_type(4)));

#if __has_builtin(__builtin_amdgcn_logf)
__device__ __forceinline__ float flog2(float x) { return __builtin_amdgcn_logf(x); }
#else
__device__ __forceinline__ float flog2(float x) { float r; asm("v_log_f32 %0, %1" : "=v"(r) : "v"(x)); return r; }
#endif
#if __has_builtin(__builtin_amdgcn_exp2f)
__device__ __forceinline__ float fexp2(float x) { return __builtin_amdgcn_exp2f(x); }
#else
__device__ __forceinline__ float fexp2(float x) { float r; asm("v_exp_f32 %0, %1" : "=v"(r) : "v"(x)); return r; }
#endif

struct Raw { f32x2 ua, ub; f32x4 m4; };

__global__ void zero_ws_kernel(float* ws) { ws[threadIdx.x] = 0.0f; }

__global__ void final_reduce_kernel(const float* __restrict__ ws, float* __restrict__ out) {
    constexpr float LN2 = 0.69314718055994530942f;
    float v = ws[threadIdx.x];   // 64 threads
    #pragma unroll
    for (int off = 32; off >= 1; off >>= 1) v += __shfl_down(v, off);
    if (threadIdx.x == 0) out[0] = v * (-LN2 / (float)M_S);
}

__global__ __launch_bounds__(256, 8) void terp_kernel(
    const float* __restrict__ x,
    const float* __restrict__ ms,
    const float* __restrict__ u,
    float* __restrict__ ws)
{
    const int lane  = threadIdx.x & 63;
    const int wave  = threadIdx.x >> 6;
    const int m     = blockIdx.x & 31;   // m fastest: 32 blocks share one ms window
    const int cg    = blockIdx.x >> 5;
    const int chunk = cg * 4 + wave;

    constexpr float LN2  = 0.69314718055994530942f;
    constexpr float invT = 1.0f / (2.5f * 0.9999f);
    constexpr float c_ms = invT / LN2;

    const float* __restrict__ u_row = u + (size_t)m * (2 * KM1);
    const float* __restrict__ msp   = ms;
    const int off0 = chunk * (2 * SPANE) + lane * 4;

    float acc = 0.0f;   // log2 units

#define LOADJ(j, R) do { \
        const int off_ = min(off0 + 256 * (j), OFF_MAX); \
        (R).ua = __builtin_nontemporal_load((const f32x2*)(u_row + off_)); \
        (R).ub = __builtin_nontemporal_load((const f32x2*)(u_row + off_ + 2)); \
        (R).m4 = *(const f32x4*)(msp + off_); \
    } while (0)

#define CALC1(u0_, u1_, m0_, m1_, t) do { \
        const float a_ = flog2(-flog2(u0_)) - flog2(-flog2(u1_)); \
        (t) = fexp2(fmaf(c_ms, (m1_) - (m0_), invT * a_)); \
    } while (0)

#define CALC2(R, ta, tb) do { \
        CALC1((R).ua.x, (R).ua.y, (R).m4.x, (R).m4.y, ta); \
        CALC1((R).ub.x, (R).ub.y, (R).m4.z, (R).m4.w, tb); \
    } while (0)

#define CONSUME(ta, tb, taN) do { \
        const float r_ = (lane == 0) ? (taN) : (ta); \
        const float v_ = __shfl(r_, (lane + 1) & 63); \
        const float selfP_ = (1.0f + (ta)) * (1.0f + (tb)); \
        const float coupP_ = fmaf((ta), (tb), 1.0f) * fmaf((tb), v_, 1.0f); \
        acc = fmaf(-2.0f, flog2(selfP_), acc + flog2(coupP_)); \
    } while (0)

    Raw R0, R1, R2;
    LOADJ(0, R0); LOADJ(1, R1); LOADJ(2, R2);

    // rotate partner for iter 15: first elem of next chunk (wave-uniform);
    // for the last chunk this is the last sampled elem (kk = KM1-1).
    float t_edge;
    {
        const int kkE = min(SPANE * (chunk + 1), KM1 - 1);
        const f32x2 uE = *(const f32x2*)(u_row + 2 * kkE);
        const f32x2 mE = *(const f32x2*)(msp + 2 * kkE);
        CALC1(uE.x, uE.y, mE.x, mE.y, t_edge);
    }

    float ta_c, tb_c;
    CALC2(R0, ta_c, tb_c);

#define STEP(j, Rn, Rl) do { \
        float ta_n_, tb_n_; CALC2(Rn, ta_n_, tb_n_); \
        if ((j) + 3 < J_IT) LOADJ((j) + 3, Rl); \
        CONSUME(ta_c, tb_c, ta_n_); \
        ta_c = ta_n_; tb_c = tb_n_; \
    } while (0)

    STEP(0,  R1, R0);  STEP(1,  R2, R1);  STEP(2,  R0, R2);
    STEP(3,  R1, R0);  STEP(4,  R2, R1);  STEP(5,  R0, R2);
    STEP(6,  R1, R0);  STEP(7,  R2, R1);  STEP(8,  R0, R2);
    STEP(9,  R1, R0);  STEP(10, R2, R1);  STEP(11, R0, R2);
    STEP(12, R1, R0);  STEP(13, R2, R1);  STEP(14, R0, R2);

    // j = 15
    if (chunk != NCHUNK - 1) {
        CONSUME(ta_c, tb_c, t_edge);
    } else {
        // Ragged tail. Lane63's clamped pair is (a = elem KM1-3? no:
        // a = 1048573 [duplicate of lane62.b], b = 1048574 [the true last]).
        // Contribution: self(b) only; rotate value = tb so lane62's second
        // coupling becomes the true (1048573,1048574) pair. Lane63's own
        // couplings are excluded (the (b, x)-coupling is the boundary term).
        const bool l63 = (lane == 63);
        const float r_ = (lane == 0) ? t_edge : (l63 ? tb_c : ta_c);
        const float v_ = __shfl(r_, (lane + 1) & 63);
        const float selfP_ = l63 ? (1.0f + tb_c) : ((1.0f + ta_c) * (1.0f + tb_c));
        const float coupP_ = l63 ? 1.0f : (fmaf(ta_c, tb_c, 1.0f) * fmaf(tb_c, v_, 1.0f));
        acc = fmaf(-2.0f, flog2(selfP_), acc + flog2(coupP_));
    }

    // boundary numerators: log2(x0 + x1*t_first) and log2(x0 + x1*t_last)
    if (lane == 0 && chunk == 0) {
        const float x0 = x[0], x1 = x[1];
        const f32x2 u0 = *(const f32x2*)u_row;
        const f32x2 m0 = *(const f32x2*)msp;
        float t1; CALC1(u0.x, u0.y, m0.x, m0.y, t1);
        acc += flog2(fmaf(x1, t1, x0));
    }
    if (lane == 0 && chunk == NCHUNK - 1) {
        const float x0 = x[0], x1 = x[1];
        const int offz = 2 * (KM1 - 1);
        const f32x2 uz = *(const f32x2*)(u_row + offz);
        const f32x2 mz = *(const f32x2*)(msp + offz);
        float tz; CALC1(uz.x, uz.y, mz.x, mz.y, tz);
        acc += flog2(fmaf(x1, tz, x0));
    }

    // wave reduce
    #pragma unroll
    for (int off = 32; off >= 1; off >>= 1) acc += __shfl_down(acc, off);

    __shared__ float ssum[4];
    if (lane == 0) ssum[wave] = acc;
    __syncthreads();
    if (threadIdx.x == 0)
        atomicAdd(&ws[blockIdx.x & (NSLOT - 1)], ssum[0] + ssum[1] + ssum[2] + ssum[3]);
}

extern "C" void kernel_launch(void* const* d_in, const int* in_sizes, int n_in,
                              void* d_out, int out_size, void* d_ws, size_t ws_size,
                              hipStream_t stream) {
    const float* x  = (const float*)d_in[0];
    const float* ms = (const float*)d_in[1];
    const float* u  = (const float*)d_in[2];

    float* ws = (float*)d_ws;
    zero_ws_kernel<<<1, NSLOT, 0, stream>>>(ws);

    dim3 grid((NCHUNK / 4) * 32);   // 4096 blocks, m fastest
    terp_kernel<<<grid, 256, 0, stream>>>(x, ms, u, ws);

    final_reduce_kernel<<<1, 64, 0, stream>>>(ws, (float*)d_out);
}

// Round 9
// 60.593 us; speedup vs baseline: 3.1727x; 3.1727x over previous
//
#include <hip/hip_runtime.h>

static constexpr int KM1     = 1048575;        // sampled elems kk in [0, KM1-1]
static constexpr int M_S     = 32;
static constexpr int J_IT    = 16;             // iters/wave, 128 elems each
static constexpr int SPANE   = 128 * J_IT;     // 2048 elems per chunk
static constexpr int NCHUNK  = 512;
static constexpr int OFF_MAX = 2 * (KM1 - 2);  // last safe float offset of a pair load
static constexpr int NBLK    = (NCHUNK / 4) * 32;   // 4096 blocks

typedef float f32x2 __attribute__((ext_vector_type(2)));
typedef float f32x4 __attribute__((ext_vector_type(4)));

#if __has_builtin(__builtin_amdgcn_logf)
__device__ __forceinline__ float flog2(float x) { return __builtin_amdgcn_logf(x); }
#else
__device__ __forceinline__ float flog2(float x) { float r; asm("v_log_f32 %0, %1" : "=v"(r) : "v"(x)); return r; }
#endif
#if __has_builtin(__builtin_amdgcn_exp2f)
__device__ __forceinline__ float fexp2(float x) { return __builtin_amdgcn_exp2f(x); }
#else
__device__ __forceinline__ float fexp2(float x) { float r; asm("v_exp_f32 %0, %1" : "=v"(r) : "v"(x)); return r; }
#endif

struct Raw { f32x2 ua, ub; f32x4 m4; };

__global__ void final_reduce_kernel(const float* __restrict__ ws, float* __restrict__ out) {
    constexpr float LN2 = 0.69314718055994530942f;
    const int lane = threadIdx.x & 63;
    const int wave = threadIdx.x >> 6;
    float v = 0.0f;
    #pragma unroll
    for (int j = 0; j < NBLK / 256; ++j) v += ws[threadIdx.x + 256 * j];
    #pragma unroll
    for (int off = 32; off >= 1; off >>= 1) v += __shfl_down(v, off);
    __shared__ float s4[4];
    if (lane == 0) s4[wave] = v;
    __syncthreads();
    if (threadIdx.x == 0)
        out[0] = (s4[0] + s4[1] + s4[2] + s4[3]) * (-LN2 / (float)M_S);
}

__global__ __launch_bounds__(256, 4) void terp_kernel(
    const float* __restrict__ x,
    const float* __restrict__ ms,
    const float* __restrict__ u,
    float* __restrict__ ws)
{
    const int lane  = threadIdx.x & 63;
    const int wave  = threadIdx.x >> 6;
    const int m     = blockIdx.x & 31;   // m fastest: 32 blocks share one ms window
    const int cg    = blockIdx.x >> 5;
    const int chunk = cg * 4 + wave;

    constexpr float LN2  = 0.69314718055994530942f;
    constexpr float invT = 1.0f / (2.5f * 0.9999f);
    constexpr float c_ms = invT / LN2;

    const float* __restrict__ u_row = u + (size_t)m * (2 * KM1);
    const float* __restrict__ msp   = ms;
    const int off0 = chunk * (2 * SPANE) + lane * 4;

    float acc = 0.0f;   // log2 units

#define LOADJ(j, R) do { \
        const int off_ = min(off0 + 256 * (j), OFF_MAX); \
        (R).ua = *(const f32x2*)(u_row + off_); \
        (R).ub = *(const f32x2*)(u_row + off_ + 2); \
        (R).m4 = *(const f32x4*)(msp + off_); \
    } while (0)

#define CALC1(u0_, u1_, m0_, m1_, t) do { \
        const float a_ = flog2(-flog2(u0_)) - flog2(-flog2(u1_)); \
        (t) = fexp2(fmaf(c_ms, (m1_) - (m0_), invT * a_)); \
    } while (0)

#define CALC2(R, ta, tb) do { \
        CALC1((R).ua.x, (R).ua.y, (R).m4.x, (R).m4.y, ta); \
        CALC1((R).ub.x, (R).ub.y, (R).m4.z, (R).m4.w, tb); \
    } while (0)

#define CONSUME(ta, tb, taN) do { \
        const float r_ = (lane == 0) ? (taN) : (ta); \
        const float v_ = __shfl(r_, (lane + 1) & 63); \
        const float selfP_ = (1.0f + (ta)) * (1.0f + (tb)); \
        const float coupP_ = fmaf((ta), (tb), 1.0f) * fmaf((tb), v_, 1.0f); \
        acc = fmaf(-2.0f, flog2(selfP_), acc + flog2(coupP_)); \
    } while (0)

    Raw R0, R1, R2, R3;
    LOADJ(0, R0); LOADJ(1, R1); LOADJ(2, R2); LOADJ(3, R3);

    // rotate partner for iter 15: first elem of next chunk (wave-uniform);
    // for the last chunk this is the last sampled elem (kk = KM1-1).
    float t_edge;
    {
        const int kkE = min(SPANE * (chunk + 1), KM1 - 1);
        const f32x2 uE = *(const f32x2*)(u_row + 2 * kkE);
        const f32x2 mE = *(const f32x2*)(msp + 2 * kkE);
        CALC1(uE.x, uE.y, mE.x, mE.y, t_edge);
    }

    float ta_c, tb_c;
    CALC2(R0, ta_c, tb_c);

#define STEP(j, Rn, Rl) do { \
        float ta_n_, tb_n_; CALC2(Rn, ta_n_, tb_n_); \
        if ((j) + 4 < J_IT) LOADJ((j) + 4, Rl); \
        CONSUME(ta_c, tb_c, ta_n_); \
        ta_c = ta_n_; tb_c = tb_n_; \
    } while (0)

    STEP(0,  R1, R0);  STEP(1,  R2, R1);  STEP(2,  R3, R2);  STEP(3,  R0, R3);
    STEP(4,  R1, R0);  STEP(5,  R2, R1);  STEP(6,  R3, R2);  STEP(7,  R0, R3);
    STEP(8,  R1, R0);  STEP(9,  R2, R1);  STEP(10, R3, R2);  STEP(11, R0, R3);
    STEP(12, R1, R0);  STEP(13, R2, R1);  STEP(14, R3, R2);

    // j = 15
    if (chunk != NCHUNK - 1) {
        CONSUME(ta_c, tb_c, t_edge);
    } else {
        // Ragged tail: lane63's clamped pair duplicates (1048573, 1048574).
        // Contribution: self(b) only; rotate value = tb so lane62's second
        // coupling becomes the true (1048573, 1048574) pair.
        const bool l63 = (lane == 63);
        const float r_ = (lane == 0) ? t_edge : (l63 ? tb_c : ta_c);
        const float v_ = __shfl(r_, (lane + 1) & 63);
        const float selfP_ = l63 ? (1.0f + tb_c) : ((1.0f + ta_c) * (1.0f + tb_c));
        const float coupP_ = l63 ? 1.0f : (fmaf(ta_c, tb_c, 1.0f) * fmaf(tb_c, v_, 1.0f));
        acc = fmaf(-2.0f, flog2(selfP_), acc + flog2(coupP_));
    }

    // boundary numerators: log2(x0 + x1*t_first) and log2(x0 + x1*t_last)
    if (lane == 0 && chunk == 0) {
        const float x0 = x[0], x1 = x[1];
        const f32x2 u0 = *(const f32x2*)u_row;
        const f32x2 m0 = *(const f32x2*)msp;
        float t1; CALC1(u0.x, u0.y, m0.x, m0.y, t1);
        acc += flog2(fmaf(x1, t1, x0));
    }
    if (lane == 0 && chunk == NCHUNK - 1) {
        const float x0 = x[0], x1 = x[1];
        const int offz = 2 * (KM1 - 1);
        const f32x2 uz = *(const f32x2*)(u_row + offz);
        const f32x2 mz = *(const f32x2*)(msp + offz);
        float tz; CALC1(uz.x, uz.y, mz.x, mz.y, tz);
        acc += flog2(fmaf(x1, tz, x0));
    }

    // wave reduce
    #pragma unroll
    for (int off = 32; off >= 1; off >>= 1) acc += __shfl_down(acc, off);

    __shared__ float ssum[4];
    if (lane == 0) ssum[wave] = acc;
    __syncthreads();
    if (threadIdx.x == 0)
        ws[blockIdx.x] = ssum[0] + ssum[1] + ssum[2] + ssum[3];   // no atomic, no pre-zero
}

extern "C" void kernel_launch(void* const* d_in, const int* in_sizes, int n_in,
                              void* d_out, int out_size, void* d_ws, size_t ws_size,
                              hipStream_t stream) {
    const float* x  = (const float*)d_in[0];
    const float* ms = (const float*)d_in[1];
    const float* u  = (const float*)d_in[2];

    float* ws = (float*)d_ws;   // NBLK floats = 16 KB

    dim3 grid(NBLK);            // 4096 blocks, m fastest
    terp_kernel<<<grid, 256, 0, stream>>>(x, ms, u, ws);

    final_reduce_kernel<<<1, 256, 0, stream>>>(ws, (float*)d_out);
}